// Round 1
// baseline (255.417 us; speedup 1.0000x reference)
//
#include <hip/hip_runtime.h>

#define KTOT 3072      // 3*1024, GEMM K
#define NROWS 8192     // bs*N rows

typedef __attribute__((ext_vector_type(8))) short bh8;   // 8 bf16 (4 VGPR)
typedef __attribute__((ext_vector_type(4))) float fx4;   // mfma acc

__device__ __forceinline__ unsigned short f2bf(float f) {
  unsigned u = __float_as_uint(f);
  u += 0x7FFFu + ((u >> 16) & 1u);     // round-to-nearest-even
  return (unsigned short)(u >> 16);
}

__device__ __forceinline__ void async_g2l16(const void* g, void* l) {
  __builtin_amdgcn_global_load_lds(
      (const __attribute__((address_space(1))) unsigned int*)g,
      (__attribute__((address_space(3))) unsigned int*)l, 16, 0, 0);
}

// ---------------- K0: BT[b][o][3m+j] = sum_f x[b][m][f] * Wcat[o][j*32+f] (bf16) ----
__global__ void k0_bt(const float* __restrict__ x, const float* __restrict__ W1,
                      const float* __restrict__ W2, unsigned short* __restrict__ bt) {
  int bid = blockIdx.x;          // 256 blocks
  int b = bid >> 5;
  int og = bid & 31;
  int t = threadIdx.x;           // 256 threads
  int oo = t >> 7;               // 0/1
  int o = og * 2 + oo;           // 0..63 (never straddles the 32 boundary)
  int mbase = (t & 127) * 8;

  const float* wrow = (o < 32) ? (W1 + o * 96) : (W2 + (o - 32) * 96);
  float wr[96];
#pragma unroll
  for (int q = 0; q < 24; ++q) {
    float4 v = ((const float4*)wrow)[q];
    wr[4*q+0] = v.x; wr[4*q+1] = v.y; wr[4*q+2] = v.z; wr[4*q+3] = v.w;
  }
  unsigned short* out = bt + (size_t)(b * 64 + o) * KTOT;
  const float* xb = x + b * (1024 * 32);
#pragma unroll 1
  for (int mm = 0; mm < 8; ++mm) {
    int m = mbase + mm;
    float xr[32];
    const float4* xp = (const float4*)(xb + m * 32);
#pragma unroll
    for (int q = 0; q < 8; ++q) {
      float4 v = xp[q];
      xr[4*q+0] = v.x; xr[4*q+1] = v.y; xr[4*q+2] = v.z; xr[4*q+3] = v.w;
    }
#pragma unroll
    for (int j = 0; j < 3; ++j) {
      float acc = 0.f;
#pragma unroll
      for (int f = 0; f < 32; ++f) acc = fmaf(xr[f], wr[j*32+f], acc);
      out[3*m + j] = f2bf(acc);
    }
  }
}

// ---------------- K1: z_pre = A(WW)*B + bias, relu half, + BN partial sums ---------
// grid 512, block 256 (4 waves). BM=16 rows/block, BN=64 (full), BK=128.
__global__ void __launch_bounds__(256) k1_gemm(
    const float* __restrict__ A,            // WW as [8192][3072] f32
    const unsigned short* __restrict__ BT,  // [8][64][3072] bf16 (B^T, k contiguous)
    const float* __restrict__ b1, const float* __restrict__ b2,
    float* __restrict__ z,                  // d_out [8192][64] f32 (pre-BN)
    float2* __restrict__ part) {            // [512][64] (sum, sumsq)
  __shared__ __align__(16) unsigned char smem[40960]; // A:2x4KB @0,4096  B:2x16KB @8192,24576

  int t = threadIdx.x;
  int w = t >> 6, l = t & 63;
  int bid = blockIdx.x;
  int r0 = bid * 16;
  int b = bid >> 6;
  const unsigned char* btb = (const unsigned char*)(BT + (size_t)b * 64 * KTOT);

  // A staging: thread t -> row=t>>4, 8 consecutive k at (t&15)*8
  int arow = t >> 4, acol = t & 15;
  const float* aptr = A + (size_t)(r0 + arow) * KTOT + acol * 8;
  int awoff = arow * 256 + ((acol * 16) ^ ((arow & 7) << 4));   // swizzled byte off

  // mfma fragment addressing (same pattern for A and B^T tiles, row-major 256B rows)
  int lr = l & 15, lg = l >> 4, swz = (l & 7) << 4;

  fx4 acc = {0.f, 0.f, 0.f, 0.f};
  float4 ra0, ra1;

  // ---- prologue: stage k-step 0 ----
  {
#pragma unroll
    for (int i = 0; i < 4; ++i) {
      int L = (w * 4 + i) * 1024 + l * 16;
      int o = L >> 8, inrow = L & 255;
      async_g2l16(btb + o * 6144 + (inrow ^ ((o & 7) << 4)),
                  smem + 8192 + (w * 4 + i) * 1024);
    }
    ra0 = ((const float4*)aptr)[0];
    ra1 = ((const float4*)aptr)[1];
    unsigned p0 = (unsigned)f2bf(ra0.x) | ((unsigned)f2bf(ra0.y) << 16);
    unsigned p1 = (unsigned)f2bf(ra0.z) | ((unsigned)f2bf(ra0.w) << 16);
    unsigned p2 = (unsigned)f2bf(ra1.x) | ((unsigned)f2bf(ra1.y) << 16);
    unsigned p3 = (unsigned)f2bf(ra1.z) | ((unsigned)f2bf(ra1.w) << 16);
    uint4 pk; pk.x = p0; pk.y = p1; pk.z = p2; pk.w = p3;
    *(uint4*)(smem + awoff) = pk;
  }
  __syncthreads();

#pragma unroll 2
  for (int s = 0; s < 24; ++s) {
    unsigned char* Ac = (s & 1) ? (smem + 4096) : smem;
    unsigned char* Bc = (s & 1) ? (smem + 24576) : (smem + 8192);
    unsigned char* An = (s & 1) ? smem : (smem + 4096);
    unsigned char* Bn = (s & 1) ? (smem + 8192) : (smem + 24576);

    if (s + 1 < 24) {
      int k0n = (s + 1) * 128;
      const unsigned char* bsrc = btb + k0n * 2;
#pragma unroll
      for (int i = 0; i < 4; ++i) {
        int L = (w * 4 + i) * 1024 + l * 16;
        int o = L >> 8, inrow = L & 255;
        async_g2l16(bsrc + o * 6144 + (inrow ^ ((o & 7) << 4)),
                    Bn + (w * 4 + i) * 1024);
      }
      ra0 = ((const float4*)(aptr + k0n))[0];
      ra1 = ((const float4*)(aptr + k0n))[1];
    }

#pragma unroll
    for (int h = 0; h < 4; ++h) {
      int ko = ((h * 64) + lg * 16) ^ swz;
      bh8 av = *(const bh8*)(Ac + lr * 256 + ko);
      bh8 bv = *(const bh8*)(Bc + (w * 16 + lr) * 256 + ko);
      acc = __builtin_amdgcn_mfma_f32_16x16x32_bf16(av, bv, acc, 0, 0, 0);
    }

    if (s + 1 < 24) {
      unsigned p0 = (unsigned)f2bf(ra0.x) | ((unsigned)f2bf(ra0.y) << 16);
      unsigned p1 = (unsigned)f2bf(ra0.z) | ((unsigned)f2bf(ra0.w) << 16);
      unsigned p2 = (unsigned)f2bf(ra1.x) | ((unsigned)f2bf(ra1.y) << 16);
      unsigned p3 = (unsigned)f2bf(ra1.z) | ((unsigned)f2bf(ra1.w) << 16);
      uint4 pk; pk.x = p0; pk.y = p1; pk.z = p2; pk.w = p3;
      *(uint4*)(An + awoff) = pk;
    }
    __syncthreads();
  }

  // ---- epilogue: bias, relu (o<32), store z_pre, BN partial sums ----
  int o = w * 16 + lr;
  float bias = (o < 32) ? b1[o] : b2[o - 32];
  float s1 = 0.f, s2 = 0.f;
#pragma unroll
  for (int r = 0; r < 4; ++r) {
    int row = r0 + lg * 4 + r;                    // C/D: col=lane&15, row=(lane>>4)*4+reg
    float v = acc[r] + bias;
    if (o < 32) v = fmaxf(v, 0.f);
    z[row * 64 + o] = v;
    s1 += v; s2 += v * v;
  }
  s1 += __shfl_xor(s1, 16); s1 += __shfl_xor(s1, 32);
  s2 += __shfl_xor(s2, 16); s2 += __shfl_xor(s2, 32);
  if (l < 16) part[bid * 64 + o] = make_float2(s1, s2);
}

// ---------------- K2: reduce partials -> scale/shift -------------------------------
__global__ void k2_stats(const float2* __restrict__ part, const float* __restrict__ gamma,
                         const float* __restrict__ beta, float2* __restrict__ stats) {
  __shared__ float red[2][8][64];
  int t = threadIdx.x;           // 512
  int o = t & 63, c = t >> 6;    // c 0..7
  float S = 0.f, Q = 0.f;
#pragma unroll 8
  for (int i = 0; i < 64; ++i) {
    float2 p = part[(c * 64 + i) * 64 + o];
    S += p.x; Q += p.y;
  }
  red[0][c][o] = S; red[1][c][o] = Q;
  __syncthreads();
  if (t < 64) {
    float Ss = 0.f, Qs = 0.f;
#pragma unroll
    for (int c2 = 0; c2 < 8; ++c2) { Ss += red[0][c2][t]; Qs += red[1][c2][t]; }
    float mean = Ss * (1.0f / 8192.0f);
    float var = Qs * (1.0f / 8192.0f) - mean * mean;
    var = fmaxf(var, 0.f);
    float rstd = rsqrtf(var + 1e-5f);
    float scale = gamma[t] * rstd;
    float shift = beta[t] - mean * scale;
    stats[t] = make_float2(scale, shift);
  }
}

// ---------------- K3: normalize in place on d_out ----------------------------------
__global__ void k3_norm(float* __restrict__ z, const float2* __restrict__ stats) {
  int i4 = blockIdx.x * 256 + threadIdx.x;   // 131072 float4's
  float4 v = ((const float4*)z)[i4];
  int o0 = (i4 & 15) * 4;
  float2 s0 = stats[o0 + 0], s1 = stats[o0 + 1], s2 = stats[o0 + 2], s3 = stats[o0 + 3];
  v.x = v.x * s0.x + s0.y;
  v.y = v.y * s1.x + s1.y;
  v.z = v.z * s2.x + s2.y;
  v.w = v.w * s3.x + s3.y;
  ((float4*)z)[i4] = v;
}

extern "C" void kernel_launch(void* const* d_in, const int* in_sizes, int n_in,
                              void* d_out, int out_size, void* d_ws, size_t ws_size,
                              hipStream_t stream) {
  const float* WW = (const float*)d_in[0];
  const float* x  = (const float*)d_in[1];
  const float* W1 = (const float*)d_in[2];
  const float* b1 = (const float*)d_in[3];
  const float* W2 = (const float*)d_in[4];
  const float* b2 = (const float*)d_in[5];
  const float* gamma = (const float*)d_in[6];
  const float* beta  = (const float*)d_in[7];

  unsigned short* bt = (unsigned short*)d_ws;                      // 3,145,728 B
  float2* part  = (float2*)((char*)d_ws + 3145728);                //   262,144 B
  float2* stats = (float2*)((char*)d_ws + 3145728 + 262144);       //       512 B
  float* z = (float*)d_out;

  hipLaunchKernelGGL(k0_bt,    dim3(256), dim3(256), 0, stream, x, W1, W2, bt);
  hipLaunchKernelGGL(k1_gemm,  dim3(512), dim3(256), 0, stream, WW, bt, b1, b2, z, part);
  hipLaunchKernelGGL(k2_stats, dim3(1),   dim3(512), 0, stream, part, gamma, beta, stats);
  hipLaunchKernelGGL(k3_norm,  dim3(512), dim3(256), 0, stream, z, stats);
}

// Round 2
// 186.933 us; speedup vs baseline: 1.3664x; 1.3664x over previous
//
#include <hip/hip_runtime.h>

typedef __attribute__((ext_vector_type(8))) short bh8;   // 8 bf16
typedef __attribute__((ext_vector_type(4))) float fx4;   // mfma acc

__device__ __forceinline__ unsigned short f2bf(float f) {
  unsigned u = __float_as_uint(f);
  u += 0x7FFFu + ((u >> 16) & 1u);     // RNE
  return (unsigned short)(u >> 16);
}

__device__ __forceinline__ void async_g2l16(const void* g, void* l) {
  __builtin_amdgcn_global_load_lds(
      (const __attribute__((address_space(1))) unsigned int*)g,
      (__attribute__((address_space(3))) unsigned int*)l, 16, 0, 0);
}

// ---------------- K0: BT[b][o][3m+j] = sum_f x[b][m][f]*Wcat[o][j*32+f] (bf16) -----
// grid 128 (8 b x 16 chunks of 64 m), block 256. LDS-staged x + W^T, uint4 writes.
__global__ void __launch_bounds__(256) k0_bt(const float* __restrict__ x,
    const float* __restrict__ W1, const float* __restrict__ W2,
    unsigned short* __restrict__ bt) {
  __shared__ float xl[64][32];     // 8 KB
  __shared__ float wl[96][64];     // 24 KB, wl[k][o] (lane-per-o conflict-free)
  int t = threadIdx.x;
  int bid = blockIdx.x;
  int b = bid >> 4, c = bid & 15;

  for (int i = t; i < 6144; i += 256) {
    int k = i >> 6, o = i & 63;
    wl[k][o] = (o < 32) ? W1[o * 96 + k] : W2[(o - 32) * 96 + k];
  }
  const float4* xs = (const float4*)(x + (size_t)(b * 1024 + c * 64) * 32);
  ((float4*)xl)[t]       = xs[t];
  ((float4*)xl)[t + 256] = xs[t + 256];
  __syncthreads();

  int o = t & 63;
  int q = t >> 6;
  unsigned short* orow = bt + (size_t)(b * 64 + o) * 3072;
#pragma unroll 1
  for (int gi = 0; gi < 2; ++gi) {
    int m0 = (q + gi * 4) * 8;
    float acc[8][3];
#pragma unroll
    for (int m = 0; m < 8; ++m) acc[m][0] = acc[m][1] = acc[m][2] = 0.f;
#pragma unroll
    for (int f4 = 0; f4 < 8; ++f4) {
      float wv[3][4];
#pragma unroll
      for (int u = 0; u < 4; ++u) {
        int f = f4 * 4 + u;
        wv[0][u] = wl[f][o];
        wv[1][u] = wl[32 + f][o];
        wv[2][u] = wl[64 + f][o];
      }
#pragma unroll
      for (int m = 0; m < 8; ++m) {
        float4 xv = *(const float4*)&xl[m0 + m][f4 * 4];
#pragma unroll
        for (int j = 0; j < 3; ++j) {
          acc[m][j] = fmaf(xv.x, wv[j][0], acc[m][j]);
          acc[m][j] = fmaf(xv.y, wv[j][1], acc[m][j]);
          acc[m][j] = fmaf(xv.z, wv[j][2], acc[m][j]);
          acc[m][j] = fmaf(xv.w, wv[j][3], acc[m][j]);
        }
      }
    }
    unsigned pk[12];
#pragma unroll
    for (int i = 0; i < 12; ++i) {
      unsigned short lo = f2bf(acc[(2 * i) / 3][(2 * i) % 3]);
      unsigned short hi = f2bf(acc[(2 * i + 1) / 3][(2 * i + 1) % 3]);
      pk[i] = (unsigned)lo | ((unsigned)hi << 16);
    }
    uint4* op = (uint4*)(orow + 3 * (c * 64 + m0));   // 48B-aligned (mult of 16)
    op[0] = make_uint4(pk[0], pk[1], pk[2], pk[3]);
    op[1] = make_uint4(pk[4], pk[5], pk[6], pk[7]);
    op[2] = make_uint4(pk[8], pk[9], pk[10], pk[11]);
  }
}

// ---------------- K1: partial GEMM, K-split x4. BM=16, BN=64, BK=64 ----------------
// grid 2048 (512 mtiles x 4 ksplits), block 256 (4 waves), LDS 20 KB -> 8 blocks/CU.
__global__ void __launch_bounds__(256, 8) k1_gemm(const float* __restrict__ A,
    const unsigned short* __restrict__ BT, float* __restrict__ parts) {
  __shared__ __align__(16) unsigned char smem[20480]; // A:2x2KB @0,2048  B:2x8KB @4096,12288
  int t = threadIdx.x;
  int w = t >> 6, l = t & 63;
  int bid = blockIdx.x;
  int ks = bid & 3, mt = bid >> 2;
  int r0 = mt * 16;
  int b = mt >> 6;
  const unsigned char* btb = (const unsigned char*)BT + (size_t)b * 393216 + ks * 1536;

  int arow = t >> 4, acol = t & 15;
  const float* aptr = A + (size_t)(r0 + arow) * 3072 + ks * 768 + acol * 4;
  int awoff = arow * 128 + ((acol * 8) ^ ((arow & 7) << 4));

  int lr = l & 15, lg = l >> 4;
  int swz = (lr & 7) << 4;

  fx4 acc = {0.f, 0.f, 0.f, 0.f};
  float4 ra;

  auto stageB = [&](unsigned char* Bn, int koff) {
#pragma unroll
    for (int i = 0; i < 2; ++i) {
      int L = i * 4096 + w * 1024 + l * 16;
      int oo = L >> 7, inrow = L & 127;
      async_g2l16(btb + (size_t)oo * 6144 + koff + (inrow ^ ((oo & 7) << 4)),
                  smem + (Bn - smem) + i * 4096 + w * 1024);
    }
  };
  auto packA = [&](unsigned char* An, float4 v) {
    unsigned p0 = (unsigned)f2bf(v.x) | ((unsigned)f2bf(v.y) << 16);
    unsigned p1 = (unsigned)f2bf(v.z) | ((unsigned)f2bf(v.w) << 16);
    *(uint2*)(An + awoff) = make_uint2(p0, p1);
  };

  stageB(smem + 4096, 0);
  ra = *(const float4*)aptr;
  packA(smem, ra);
  __syncthreads();

#pragma unroll 2
  for (int s = 0; s < 12; ++s) {
    unsigned char* Ac = smem + (s & 1) * 2048;
    unsigned char* Bc = smem + 4096 + (s & 1) * 8192;
    unsigned char* An = smem + ((s + 1) & 1) * 2048;
    unsigned char* Bn = smem + 4096 + ((s + 1) & 1) * 8192;
    if (s < 11) {
      stageB(Bn, (s + 1) * 128);
      ra = *(const float4*)(aptr + (s + 1) * 64);
    }
#pragma unroll
    for (int sub = 0; sub < 2; ++sub) {
      int ko = (sub * 64 + lg * 16) ^ swz;
      bh8 av = *(const bh8*)(Ac + lr * 128 + ko);
      bh8 bv = *(const bh8*)(Bc + (w * 16 + lr) * 128 + ko);
      acc = __builtin_amdgcn_mfma_f32_16x16x32_bf16(av, bv, acc, 0, 0, 0);
    }
    if (s < 11) packA(An, ra);
    __syncthreads();
  }

  float* pout = parts + (size_t)ks * 524288 + (size_t)r0 * 64 + w * 16 + lr;
#pragma unroll
  for (int r = 0; r < 4; ++r)
    pout[(lg * 4 + r) * 64] = acc[r];   // C/D: col=lane&15, row=(lane>>4)*4+r
}

// ---------------- K2: sum 4 partials + bias + relu -> z, BN per-block sums ---------
__global__ void __launch_bounds__(256) k2_red(const float* __restrict__ parts,
    const float* __restrict__ b1, const float* __restrict__ b2,
    float* __restrict__ z, float2* __restrict__ part2) {
  __shared__ float4 redA[4][16], redB[4][16];
  int t = threadIdx.x, bid = blockIdx.x;
  int w = t >> 6, l = t & 63;
  int o0 = (t & 15) * 4;
  float4 bias = (o0 < 32) ? ((const float4*)b1)[o0 >> 2]
                          : ((const float4*)b2)[(o0 - 32) >> 2];
  bool rl = (o0 < 32);
  float4 s1 = {0.f, 0.f, 0.f, 0.f}, s2 = {0.f, 0.f, 0.f, 0.f};
  const float4* p0 = (const float4*)parts;
#pragma unroll
  for (int k = 0; k < 4; ++k) {
    int i4 = bid * 1024 + k * 256 + t;
    float4 v  = p0[i4];
    float4 v1 = p0[131072 + i4];
    float4 v2 = p0[262144 + i4];
    float4 v3 = p0[393216 + i4];
    v.x += v1.x + v2.x + v3.x + bias.x;
    v.y += v1.y + v2.y + v3.y + bias.y;
    v.z += v1.z + v2.z + v3.z + bias.z;
    v.w += v1.w + v2.w + v3.w + bias.w;
    if (rl) {
      v.x = fmaxf(v.x, 0.f); v.y = fmaxf(v.y, 0.f);
      v.z = fmaxf(v.z, 0.f); v.w = fmaxf(v.w, 0.f);
    }
    ((float4*)z)[i4] = v;
    s1.x += v.x; s1.y += v.y; s1.z += v.z; s1.w += v.w;
    s2.x += v.x * v.x; s2.y += v.y * v.y; s2.z += v.z * v.z; s2.w += v.w * v.w;
  }
#define RED_(c) { s1.c += __shfl_xor(s1.c, 16); s1.c += __shfl_xor(s1.c, 32); \
                  s2.c += __shfl_xor(s2.c, 16); s2.c += __shfl_xor(s2.c, 32); }
  RED_(x) RED_(y) RED_(z) RED_(w)
#undef RED_
  if (l < 16) { redA[w][l] = s1; redB[w][l] = s2; }
  __syncthreads();
  if (t < 16) {
    float4 S = redA[0][t], Q = redB[0][t];
#pragma unroll
    for (int wv = 1; wv < 4; ++wv) {
      float4 a = redA[wv][t], q = redB[wv][t];
      S.x += a.x; S.y += a.y; S.z += a.z; S.w += a.w;
      Q.x += q.x; Q.y += q.y; Q.z += q.z; Q.w += q.w;
    }
    int ob = bid * 64 + t * 4;
    part2[ob + 0] = make_float2(S.x, Q.x);
    part2[ob + 1] = make_float2(S.y, Q.y);
    part2[ob + 2] = make_float2(S.z, Q.z);
    part2[ob + 3] = make_float2(S.w, Q.w);
  }
}

// ---------------- K3: reduce 128 block-partials -> scale/shift ---------------------
__global__ void k3_stats(const float2* __restrict__ part2, const float* __restrict__ gamma,
                         const float* __restrict__ beta, float2* __restrict__ stats) {
  __shared__ float red[2][4][64];
  int t = threadIdx.x;           // 256
  int o = t & 63, c = t >> 6;    // c 0..3
  float S = 0.f, Q = 0.f;
#pragma unroll 4
  for (int i = 0; i < 32; ++i) {
    float2 p = part2[(c * 32 + i) * 64 + o];
    S += p.x; Q += p.y;
  }
  red[0][c][o] = S; red[1][c][o] = Q;
  __syncthreads();
  if (t < 64) {
    float Ss = 0.f, Qs = 0.f;
#pragma unroll
    for (int cc = 0; cc < 4; ++cc) { Ss += red[0][cc][t]; Qs += red[1][cc][t]; }
    float mean = Ss * (1.0f / 8192.0f);
    float var = fmaxf(Qs * (1.0f / 8192.0f) - mean * mean, 0.f);
    float rstd = rsqrtf(var + 1e-5f);
    float scale = gamma[t] * rstd;
    stats[t] = make_float2(scale, beta[t] - mean * scale);
  }
}

// ---------------- K4: normalize in place on d_out ----------------------------------
__global__ void k4_norm(float* __restrict__ z, const float2* __restrict__ stats) {
  int i4 = blockIdx.x * 256 + threadIdx.x;   // 131072 float4's
  float4 v = ((const float4*)z)[i4];
  int o0 = (i4 & 15) * 4;
  float2 s0 = stats[o0 + 0], s1 = stats[o0 + 1], s2 = stats[o0 + 2], s3 = stats[o0 + 3];
  v.x = v.x * s0.x + s0.y;
  v.y = v.y * s1.x + s1.y;
  v.z = v.z * s2.x + s2.y;
  v.w = v.w * s3.x + s3.y;
  ((float4*)z)[i4] = v;
}

extern "C" void kernel_launch(void* const* d_in, const int* in_sizes, int n_in,
                              void* d_out, int out_size, void* d_ws, size_t ws_size,
                              hipStream_t stream) {
  const float* WW = (const float*)d_in[0];
  const float* x  = (const float*)d_in[1];
  const float* W1 = (const float*)d_in[2];
  const float* b1 = (const float*)d_in[3];
  const float* W2 = (const float*)d_in[4];
  const float* b2 = (const float*)d_in[5];
  const float* gamma = (const float*)d_in[6];
  const float* beta  = (const float*)d_in[7];

  unsigned short* bt = (unsigned short*)d_ws;                       // 3,145,728 B
  float*  parts = (float*)((char*)d_ws + 3145728);                  // 8,388,608 B
  float2* part2 = (float2*)((char*)d_ws + 11534336);                //    65,536 B
  float2* stats = (float2*)((char*)d_ws + 11599872);                //       512 B
  float* z = (float*)d_out;

  hipLaunchKernelGGL(k0_bt,    dim3(128),  dim3(256), 0, stream, x, W1, W2, bt);
  hipLaunchKernelGGL(k1_gemm,  dim3(2048), dim3(256), 0, stream, WW, bt, parts);
  hipLaunchKernelGGL(k2_red,   dim3(128),  dim3(256), 0, stream, parts, b1, b2, z, part2);
  hipLaunchKernelGGL(k3_stats, dim3(1),    dim3(256), 0, stream, part2, gamma, beta, stats);
  hipLaunchKernelGGL(k4_norm,  dim3(512),  dim3(256), 0, stream, z, stats);
}